// Round 1
// baseline (16769.131 us; speedup 1.0000x reference)
//
#include <hip/hip_runtime.h>

#define Bsz 1024
#define Tn  256
#define Fn  128
#define Hn  16

// ---------- fast activations (branch-free, saturating) ----------
__device__ __forceinline__ float frcp(float x) { return __builtin_amdgcn_rcpf(x); }
__device__ __forceinline__ float fexp(float x) { return __expf(x); }          // v_exp_f32 path
__device__ __forceinline__ float sigm(float x) { return frcp(1.0f + fexp(-x)); }
__device__ __forceinline__ float tanh_fast(float x) {
    // tanh(x) = 1 - 2/(exp(2x)+1); exp->inf/0 saturates correctly
    return 1.0f - 2.0f * frcp(fexp(2.0f * x) + 1.0f);
}

// ---------- kernel 1: transpose x (B,T,F) -> xt (T,F,B) ----------
__global__ __launch_bounds__(256) void transpose_x(const float* __restrict__ x,
                                                   float* __restrict__ xt) {
    __shared__ float tile[32][33];
    const int t  = blockIdx.z;
    const int bb = blockIdx.x * 32;
    const int ff = blockIdx.y * 32;
    const int tx = threadIdx.x;   // 0..31
    const int ty = threadIdx.y;   // 0..7
#pragma unroll
    for (int i = 0; i < 4; ++i) {
        int brow = ty + i * 8;
        tile[brow][tx] = x[((size_t)(bb + brow) * Tn + t) * Fn + (ff + tx)];
    }
    __syncthreads();
#pragma unroll
    for (int i = 0; i < 4; ++i) {
        int frow = ty + i * 8;
        xt[((size_t)t * Fn + (ff + frow)) * Bsz + (bb + tx)] = tile[tx][frow];
    }
}

// ---------- kernel 2: bsum = b_ih + b_hh  (F*64 elems) ----------
__global__ void prep_bsum(const float* __restrict__ bih, const float* __restrict__ bhh,
                          float* __restrict__ bsum) {
    int i = blockIdx.x * 256 + threadIdx.x;
    if (i < Fn * 64) bsum[i] = bih[i] + bhh[i];
}

// ---------- kernel 3: the recurrent LSTM ----------
// block: 256 threads = 256 batch elems, one feature per blockIdx.x
// weights are wave-uniform -> scalar loads; h,c live in VGPRs
__global__ __launch_bounds__(256) void lstm_fwd(const float* __restrict__ xt,
                                                const float* __restrict__ Wih,   // (F,64)
                                                const float* __restrict__ Whh,   // (F,64,16)
                                                const float* __restrict__ bsum,  // (F,64)
                                                const float* __restrict__ init_h,
                                                const float* __restrict__ init_c,
                                                float* __restrict__ hout) {      // (F*16, B)
    const int f = blockIdx.x;
    const int b = blockIdx.y * 256 + threadIdx.x;

    const float* __restrict__ W   = Whh  + (size_t)f * 64 * 16;
    const float* __restrict__ Wx  = Wih  + (size_t)f * 64;
    const float* __restrict__ Bs  = bsum + (size_t)f * 64;

    float h[16], c[16];
#pragma unroll
    for (int j = 0; j < 16; ++j) {
        h[j] = init_h[f * 16 + j];
        c[j] = init_c[f * 16 + j];
    }

    const float* xp = xt + (size_t)f * Bsz + b;

    for (int t = 0; t < Tn; ++t) {
        const float xv = xp[(size_t)t * Fn * Bsz];
        float hn[16];
#pragma unroll
        for (int j = 0; j < 16; ++j) {
            float gi = __fmaf_rn(xv, Wx[j],      Bs[j]);
            float gf = __fmaf_rn(xv, Wx[16 + j], Bs[16 + j]);
            float gg = __fmaf_rn(xv, Wx[32 + j], Bs[32 + j]);
            float go = __fmaf_rn(xv, Wx[48 + j], Bs[48 + j]);
#pragma unroll
            for (int k = 0; k < 16; ++k) {
                const float hk = h[k];
                gi = __fmaf_rn(W[(j)      * 16 + k], hk, gi);
                gf = __fmaf_rn(W[(16 + j) * 16 + k], hk, gf);
                gg = __fmaf_rn(W[(32 + j) * 16 + k], hk, gg);
                go = __fmaf_rn(W[(48 + j) * 16 + k], hk, go);
            }
            const float ig = sigm(gi);
            const float fg = sigm(gf);
            const float gv = tanh_fast(gg);
            const float og = sigm(go);
            const float cj = __fmaf_rn(fg, c[j], ig * gv);
            c[j]  = cj;
            hn[j] = og * tanh_fast(cj);
        }
#pragma unroll
        for (int j = 0; j < 16; ++j) h[j] = hn[j];
    }

#pragma unroll
    for (int j = 0; j < 16; ++j)
        hout[(size_t)(f * 16 + j) * Bsz + b] = h[j];
}

// ---------- kernel 4: out[b] = b_fuse + sum_k hout[k][b]*W_fuse[k] ----------
__global__ __launch_bounds__(256) void fuse_out(const float* __restrict__ hout,
                                                const float* __restrict__ Wf,
                                                const float* __restrict__ bf,
                                                float* __restrict__ out) {
    const int b = blockIdx.x * 256 + threadIdx.x;
    float acc = bf[0];
#pragma unroll 8
    for (int k = 0; k < Fn * Hn; ++k)
        acc = __fmaf_rn(hout[(size_t)k * Bsz + b], Wf[k], acc);
    out[b] = acc;
}

extern "C" void kernel_launch(void* const* d_in, const int* in_sizes, int n_in,
                              void* d_out, int out_size, void* d_ws, size_t ws_size,
                              hipStream_t stream) {
    const float* x      = (const float*)d_in[0];
    const float* Wih    = (const float*)d_in[1];
    const float* Whh    = (const float*)d_in[2];
    const float* bih    = (const float*)d_in[3];
    const float* bhh    = (const float*)d_in[4];
    const float* init_h = (const float*)d_in[5];
    const float* init_c = (const float*)d_in[6];
    const float* Wf     = (const float*)d_in[7];
    const float* bf     = (const float*)d_in[8];
    float* out = (float*)d_out;

    char* ws = (char*)d_ws;
    float* xt   = (float*)ws;                                  // 134,217,728 B
    float* bsum = (float*)(ws + (size_t)134217728);            // 32 KB
    float* hout = (float*)(ws + (size_t)134217728 + 32768);    // 8.4 MB

    transpose_x<<<dim3(32, 4, 256), dim3(32, 8), 0, stream>>>(x, xt);
    prep_bsum<<<32, 256, 0, stream>>>(bih, bhh, bsum);
    lstm_fwd<<<dim3(Fn, Bsz / 256), 256, 0, stream>>>(xt, Wih, Whh, bsum, init_h, init_c, hout);
    fuse_out<<<Bsz / 256, 256, 0, stream>>>(hout, Wf, bf, out);
}